// Round 17
// baseline (146.510 us; speedup 1.0000x reference)
//
#include <hip/hip_runtime.h>

// Capsule EM routing. B=32, H=W=8, I=32 -> N=2048, O=64, P=16, routings=3.
//
// R17: un-starve the register allocator. R16's prefetch was null (bench
// 146.1 ~= R15 146.7) -> scalar-load latency exonerated; 6 stall theories
// dead. Register arithmetic finally explains the residual ~12us/pass body
// stall: live loop state = acc(33) + v(16) + w(16) = 65 floats BEFORE
// m[16]/i2v[16]/zzbK -- at the heuristic 64-VGPR allocation
// (launch_bounds(1024) targets 2 blocks/CU) the stats CANNOT be register-
// resident, so the compiler re-reads stats_s from LDS inside the loop
// (up to 32 ds_read/iter = the hidden DS traffic R15 only half-removed).
// Fix: __launch_bounds__(1024, 1) -- under hipcc's CUDA-style second-arg
// (R3-measured) this is 1 block/CU -> VGPR cap 128 -> ~115-float working
// set fits. Occupancy 32 -> 16 waves/CU (R1->R5: occupancy 8<->32 moved
// accum <10%, acceptable trade). Unlike R2's (1024,8) this RAISES the cap;
// it cannot force a spill. Everything else bit-identical to R15.
// Kept lessons: no unroll pragmas (R4), no LDS fp32 atomics (R3), no grid
// sync (R6/R10), one coop atomic flush (R13), stable (v-m)^2 math (R11),
// max-hoisted softmax + SMEM pose/act (R15, absmax-verified).

#define NB 32
#define NN 2048
#define NO 64
#define NP 16
#define EPSF 1e-7f

// block tiling: 8 sites x 16 i per block; 16 blocks per batch
#define SITES_PB 8
#define IS_PB 16

#define ACC_SLOTS 33
#define ACC_PER_B (ACC_SLOTS * NO)    // 2112 floats
#define ACC_TOTAL (NB * ACC_PER_B)    // 67584 floats

template <bool FIRST>
__global__ __launch_bounds__(1024, 1) void accum_kernel(
    const float* __restrict__ pose,        // [B][N][16]
    const float* __restrict__ act,         // [B][N]
    const float* __restrict__ wmat,        // [32][64][16]
    const float* __restrict__ beta_v,      // [64]
    const float* __restrict__ beta_a,      // [64]
    const float* __restrict__ accum_prev,  // [B][33][64] summed, or null
    float* __restrict__ accum_out,         // [B][33][64] pre-zeroed
    float inv_temp)                        // temperature of the PREV iter
{
    __shared__ float stats_s[ACC_PER_B];      // 8448 B (slot32 = zzb - K)
    __shared__ float buf[4][ACC_PER_B];       // 33.8 KB reduce buffers

    const int b = blockIdx.y;
    const int sg = blockIdx.x >> 1;           // site-group 0..7 (8 sites)
    const int ig = blockIdx.x & 1;            // i-group 0..1 (16 i)
    const int s0 = sg * SITES_PB;
    const int tid = threadIdx.x;
    const int w = tid >> 6;                   // wave 0..15 -> i = ig*16+w
    const int o = tid & 63;                   // lane = output capsule
    const int i = ig * 16 + w;
    const int grp = w >> 2, wvin = w & 3;     // reduce grouping

    // ---- wave-persistent w row: loaded once ----
    const float4* wp = (const float4*)(wmat + ((size_t)i * 64 + o) * 16);
    float4 w0 = wp[0], w1 = wp[1], w2 = wp[2], w3 = wp[3];

    // ---- stats of previous pass: WAVE 0 ONLY -> stats_s ----
    if (!FIRST && tid < 64) {
        const float* ap = accum_prev + (size_t)b * ACC_PER_B;
        float rps = ap[32 * 64 + o];
        float rinv = 1.0f / rps;
        float logsum = 0.f;
        float mm[16], vv[16];
        #pragma unroll
        for (int p = 0; p < 16; p++) {
            float mv = ap[p * 64 + o] * rinv;
            float va = fmaxf(ap[(16 + p) * 64 + o] * rinv - mv * mv, 0.f);
            mm[p] = mv;
            vv[p] = va;
            logsum += __logf(sqrtf(va) + EPSF);
        }
        float cost = rps * (16.0f * beta_v[o] + logsum);
        float cm = cost;
        #pragma unroll
        for (int s = 32; s > 0; s >>= 1) cm += __shfl_xor(cm, s, 64);
        cm *= (1.0f / 64.0f);
        float dd = cost - cm;
        float cs = dd * dd;
        #pragma unroll
        for (int s = 32; s > 0; s >>= 1) cs += __shfl_xor(cs, s, 64);
        cs = sqrtf(cs * (1.0f / 64.0f));
        float x = inv_temp * (beta_a[o] + (cm - cost) / (cs + EPSF));
        float oa = 1.0f / (1.0f + __expf(-x));
        float zzb = __logf(oa + EPSF) - logsum;
        // softmax shift constant: K = max over the 64 o-lanes of zzb
        float K = zzb;
        #pragma unroll
        for (int s = 32; s > 0; s >>= 1) K = fmaxf(K, __shfl_xor(K, s, 64));
        #pragma unroll
        for (int p = 0; p < 16; p++) stats_s[p * 64 + o] = mm[p];
        #pragma unroll
        for (int p = 0; p < 16; p++) stats_s[(16 + p) * 64 + o] = 0.5f / vv[p];
        stats_s[32 * 64 + o] = zzb - K;
    }
    __syncthreads();   // stats visible

    float m[16], i2v[16], zzbK = 0.f;
    if (!FIRST) {
        #pragma unroll
        for (int p = 0; p < 16; p++) m[p] = stats_s[p * 64 + o];
        #pragma unroll
        for (int p = 0; p < 16; p++) i2v[p] = stats_s[(16 + p) * 64 + o];
        zzbK = stats_s[32 * 64 + o];
    }

    float accR = 0.f, acc1[16], acc2[16];
    #pragma unroll
    for (int p = 0; p < 16; p++) { acc1[p] = 0.f; acc2[p] = 0.f; }

    // wave-uniform base index for scalar pose/act loads
    const int base_n = __builtin_amdgcn_readfirstlane(s0 * 32 + ig * 16 + w);
    const float* pose_b = pose + (size_t)b * NN * 16;
    const float* act_b  = act + (size_t)b * NN;

    // ---- inner loop: zero LDS reads; pose/act on the SMEM pipe ----
    for (int sl = 0; sl < 8; sl++) {
        const int site = s0 + sl;
        const float c0 = ((site >> 3) + 0.5f) * 0.125f;
        const float c1 = ((site & 7) + 0.5f) * 0.125f;
        const int n = base_n + sl * 32;                 // wave-uniform
        const float4* pr4 = (const float4*)(pose_b + (size_t)n * 16);
        const float av = act_b[n];                      // scalar load

        float v[16];
        #pragma unroll
        for (int a = 0; a < 4; a++) {
            float4 pa = pr4[a];                         // s_load_dwordx4
            v[a * 4 + 0] = pa.x * w0.x + pa.y * w1.x + pa.z * w2.x + pa.w * w3.x;
            v[a * 4 + 1] = pa.x * w0.y + pa.y * w1.y + pa.z * w2.y + pa.w * w3.y;
            v[a * 4 + 2] = pa.x * w0.z + pa.y * w1.z + pa.z * w2.z + pa.w * w3.z;
            v[a * 4 + 3] = pa.x * w0.w + pa.y * w1.w + pa.z * w2.w + pa.w * w3.w;
        }
        v[0] += c0;
        v[1] += c1;

        float rr;
        if (FIRST) {
            rr = 1.0f / 64.0f;
        } else {
            float d = zzbK;
            #pragma unroll
            for (int p = 0; p < 16; p++) {
                float t = v[p] - m[p];
                d -= t * t * i2v[p];
            }
            // shifted softmax: exponent <= 0 by construction (no max pass)
            float e = __expf(d);
            float sum = e;
            #pragma unroll
            for (int s = 32; s > 0; s >>= 1) sum += __shfl_xor(sum, s, 64);
            rr = e / fmaxf(sum, 1e-30f);
        }
        float rp = rr * av;
        accR += rp;
        #pragma unroll
        for (int p = 0; p < 16; p++) {
            acc1[p] += rp * v[p];
            acc2[p] += rp * v[p] * v[p];
        }
    }

    // ---- R5-proven reduce: barrier-sequenced in-place adds per group ----
    if (wvin == 3) {
        float* r = buf[grp];
        r[32 * 64 + o] = accR;
        #pragma unroll
        for (int p = 0; p < 16; p++) r[p * 64 + o] = acc1[p];
        #pragma unroll
        for (int p = 0; p < 16; p++) r[(16 + p) * 64 + o] = acc2[p];
    }
    __syncthreads();
    if (wvin == 2) {
        float* r = buf[grp];
        r[32 * 64 + o] += accR;
        #pragma unroll
        for (int p = 0; p < 16; p++) r[p * 64 + o] += acc1[p];
        #pragma unroll
        for (int p = 0; p < 16; p++) r[(16 + p) * 64 + o] += acc2[p];
    }
    __syncthreads();
    if (wvin == 1) {
        float* r = buf[grp];
        r[32 * 64 + o] += accR;
        #pragma unroll
        for (int p = 0; p < 16; p++) r[p * 64 + o] += acc1[p];
        #pragma unroll
        for (int p = 0; p < 16; p++) r[(16 + p) * 64 + o] += acc2[p];
    }
    __syncthreads();
    if (wvin == 0) {
        float* r = buf[grp];
        r[32 * 64 + o] += accR;
        #pragma unroll
        for (int p = 0; p < 16; p++) r[p * 64 + o] += acc1[p];
        #pragma unroll
        for (int p = 0; p < 16; p++) r[(16 + p) * 64 + o] += acc2[p];
    }
    __syncthreads();

    // ---- ONE cooperative flush: ~2 coalesced atomics per thread ----
    float* ac = accum_out + (size_t)b * ACC_PER_B;
    for (int j = tid; j < ACC_PER_B; j += 1024)
        atomicAdd(ac + j, buf[0][j] + buf[1][j] + buf[2][j] + buf[3][j]);
}

__global__ __launch_bounds__(64) void stats_final(
    const float* __restrict__ accum,   // [B][33][64] summed
    const float* __restrict__ beta_v,  // [64]
    const float* __restrict__ beta_a,  // [64]
    float* __restrict__ out,
    float inv_temp)
{
    const int b = blockIdx.x;
    const int o = threadIdx.x;  // 64 threads = 1 wave
    const float* ac = accum + (size_t)b * ACC_PER_B;

    float rps = ac[32 * 64 + o];
    float rinv = 1.0f / rps;
    float m[16];
    float logsum = 0.f;
    #pragma unroll
    for (int p = 0; p < 16; p++) {
        float mm = ac[p * 64 + o] * rinv;
        float vv = fmaxf(ac[(16 + p) * 64 + o] * rinv - mm * mm, 0.f);
        m[p] = mm;
        logsum += __logf(sqrtf(vv) + EPSF);
    }
    float cost = rps * (16.0f * beta_v[o] + logsum);

    float cm = cost;
    #pragma unroll
    for (int s = 32; s > 0; s >>= 1) cm += __shfl_xor(cm, s, 64);
    cm *= (1.0f / 64.0f);
    float dd = cost - cm;
    float cs = dd * dd;
    #pragma unroll
    for (int s = 32; s > 0; s >>= 1) cs += __shfl_xor(cs, s, 64);
    cs = sqrtf(cs * (1.0f / 64.0f));

    float x = inv_temp * (beta_a[o] + (cm - cost) / (cs + EPSF));
    float oa = 1.0f / (1.0f + __expf(-x));

    float* op = out + ((size_t)b * 64 + o) * 16;
    #pragma unroll
    for (int p = 0; p < 16; p++) op[p] = m[p];
    out[(size_t)NB * NO * NP + (size_t)b * 64 + o] = oa;
}

extern "C" void kernel_launch(void* const* d_in, const int* in_sizes, int n_in,
                              void* d_out, int out_size, void* d_ws, size_t ws_size,
                              hipStream_t stream) {
    const float* pose   = (const float*)d_in[0];  // (32,8,8,32,4,4)
    const float* act    = (const float*)d_in[1];  // (32,8,8,32)
    const float* wmat   = (const float*)d_in[2];  // (32,64,4,4)
    const float* beta_v = (const float*)d_in[3];  // (1,64)
    const float* beta_a = (const float*)d_in[4];  // (1,64)
    float* out = (float*)d_out;
    float* ws = (float*)d_ws;

    float* a0 = ws;
    float* a1 = ws + (size_t)ACC_TOTAL;
    float* a2 = ws + 2 * (size_t)ACC_TOTAL;

    // zero the three atomic accumulators (ws is poisoned before every call)
    hipMemsetAsync(ws, 0, 3 * (size_t)ACC_TOTAL * sizeof(float), stream);

    dim3 grid(16, NB);   // 512 WGs x 1024 thd
    accum_kernel<true ><<<grid, 1024, 0, stream>>>(pose, act, wmat, beta_v, beta_a,
                                                   nullptr, a0, 0.0f);
    accum_kernel<false><<<grid, 1024, 0, stream>>>(pose, act, wmat, beta_v, beta_a,
                                                   a0, a1, 1.0f);
    accum_kernel<false><<<grid, 1024, 0, stream>>>(pose, act, wmat, beta_v, beta_a,
                                                   a1, a2, 2.0f);
    stats_final<<<NB, 64, 0, stream>>>(a2, beta_v, beta_a, out, 3.0f);
}